// Round 10
// baseline (145.439 us; speedup 1.0000x reference)
//
#include <hip/hip_runtime.h>

// Voxelizer: V = 64^3 voxels over [-1,1]^3, N = 4096 anisotropic Gaussians.
// out[v] = packed bf16 pair: low16 = sum(resp*dB), high16 = sum(resp*dA),
//   resp = exp2(q), q = degree-2 poly in voxel coords (-0.5*log2(e) folded in).
//
// Layout (established r0-r9, PASSING since r6):
//   d_in : fp32. [0] pos [N,3], [1] cov [N,3,3], [2] dA, [3] dB
//   d_out: 524288 bf16 = u32 per voxel (low=dB-sum, high=dA-sum)
//
// r9 post-mortem: 117us, VALUBusy 61% -- 32 barriers/block + per-chunk staging
// + block imbalance leave 39% idle.
// r10: coefficients precomputed ONCE to d_ws table (192KiB, ws_size-guarded);
//      per-block: ONE bound-test/compaction pass (LDS offset list), then
//      barrier-free inner loop over survivors (broadcast global loads from
//      L2-resident table); QCUT -18; scattered brick mapping for balance.

#ifndef __has_builtin
#define __has_builtin(x) 0
#endif

using u16 = unsigned short;
using u32 = unsigned int;
using u64 = unsigned long long;

__device__ __forceinline__ u16 f2bf(float f) {   // fp32 -> bf16, RNE
    u32 x = __float_as_uint(f);
    x += 0x7FFFu + ((x >> 16) & 1u);
    return (u16)(x >> 16);
}

__device__ __forceinline__ float exp2_fast(float x) {
#if __has_builtin(__builtin_amdgcn_exp2f)
    return __builtin_amdgcn_exp2f(x);            // v_exp_f32
#else
    return exp2f(x);
#endif
}

constexpr float QCUT = -18.0f;       // drop pairs with resp < 2^-18

// ---------------- prepass: per-gaussian polynomial coefficients ----------
__global__ __launch_bounds__(256) void vox_prep(
    const float* __restrict__ pos, const float* __restrict__ cov,
    const float* __restrict__ dA,  const float* __restrict__ dB,
    float4* __restrict__ cft, int N)
{
    int n = blockIdx.x * 256 + threadIdx.x;
    if (n >= N) return;
    const float sc = -0.7213475204444817f;   // -0.5 * log2(e)
    float p0 = pos[3 * n + 0], p1 = pos[3 * n + 1], p2 = pos[3 * n + 2];
    const float* c = cov + 9 * n;
    float c00 = c[0], c01 = c[1], c02 = c[2];
    float c10 = c[3], c11 = c[4], c12 = c[5];
    float c20 = c[6], c21 = c[7], c22 = c[8];
    float s01 = c01 + c10, s02 = c02 + c20, s12 = c12 + c21;
    float k0 = sc * (c00 * p0 * p0 + c11 * p1 * p1 + c22 * p2 * p2
                     + s01 * p0 * p1 + s02 * p0 * p2 + s12 * p1 * p2);
    float kz = -sc * (2.0f * c00 * p0 + s01 * p1 + s02 * p2);
    float kx = -sc * (s01 * p0 + 2.0f * c11 * p1 + s12 * p2);
    float ky = -sc * (s02 * p0 + s12 * p1 + 2.0f * c22 * p2);
    cft[3 * n + 0] = make_float4(k0, kz, kx, ky);
    cft[3 * n + 1] = make_float4(sc * c00, sc * c11, sc * c22, sc * s01);
    cft[3 * n + 2] = make_float4(sc * s02, sc * s12, dA[n], dB[n]);
}

// ---------------- main: brick = 4(z) x 8(x) x 8(y) voxels ----------------
// 1024 blocks x 256 threads (4 waves). Phase 1: wave qw bound-tests
// gaussians [qw*1024,(qw+1)*1024) vs the brick, compacts byte-offsets into
// list[qw][]. Phase 2 (barrier-free): each wave covers all 256 voxels,
// iterating every segment stride-4 from offset qw. Final LDS combine.
__global__ __launch_bounds__(256, 4) void vox_main(
    const float4* __restrict__ cft,  // [N*3] coefficient table (d_ws)
    u32* __restrict__ out,           // [VTOT] packed (dB | dA<<16)
    int N)
{
    __shared__ u32   list[4][1024];          // 16 KB survivor byte-offsets
    __shared__ int   wcnt[4];
    __shared__ float cbuf[4][64][4][2];      // 8 KB combine

    const int t    = threadIdx.x;
    const int qw   = t >> 6;
    const int lane = t & 63;
    const int b    = (blockIdx.x * 331) & 1023;  // scattered brick mapping
    const int bz = b >> 6, bx = (b >> 3) & 7, by = b & 7;

    const int s = lane;
    const int dz = s >> 4, dx = (s >> 1) & 7, dyq = s & 1;
    const int iz = bz * 4 + dz, ix = bx * 8 + dx, iy0 = by * 8 + dyq * 4;

    const float step = 2.0f / 63.0f;
    const float z = -1.0f + step * (float)iz;
    const float x = -1.0f + step * (float)ix;
    const float zz = z * z, xx = x * x, zx = z * x;
    float y[4], yy[4];
#pragma unroll
    for (int i = 0; i < 4; ++i) {
        y[i] = -1.0f + step * (float)(iy0 + i);
        yy[i] = y[i] * y[i];
    }

    // brick center / half-extents (voxel-center span)
    const float zc = -1.0f + step * ((float)(bz * 4) + 1.5f);
    const float xc = -1.0f + step * ((float)(bx * 8) + 3.5f);
    const float yc = -1.0f + step * ((float)(by * 8) + 3.5f);
    const float hz = 1.5f * step, hx = 3.5f * step, hy = 3.5f * step;

    // ---- phase 1: bound test + wave-local compaction ----
    {
        int cnt = 0;
        for (int sub = 0; sub < 16; ++sub) {
            int n = qw * 1024 + sub * 64 + lane;
            bool pred = false;
            if (n < N) {
                float4 F0 = cft[3 * n + 0];
                float4 F1 = cft[3 * n + 1];
                float4 F2 = cft[3 * n + 2];
                float k0 = F0.x, kz = F0.y, kx = F0.z, ky = F0.w;
                float kzz = F1.x, kxx = F1.y, kyy = F1.z, kzx = F1.w;
                float kzy = F2.x, kxy = F2.y;
                float bc = fmaf(kz, zc, k0);
                bc = fmaf(kzz, zc * zc, bc);
                bc = fmaf(kx, xc, bc);
                bc = fmaf(kxx, xc * xc, bc);
                bc = fmaf(kzx, zc * xc, bc);
                float cy0 = fmaf(kzy, zc, ky);
                cy0 = fmaf(kxy, xc, cy0);
                float qc = fmaf(kyy, yc * yc, fmaf(cy0, yc, bc));
                float gz = fmaf(2.0f * kzz, zc, kz);
                gz = fmaf(kzx, xc, gz); gz = fmaf(kzy, yc, gz);
                float gx = fmaf(2.0f * kxx, xc, kx);
                gx = fmaf(kzx, zc, gx); gx = fmaf(kxy, yc, gx);
                float gy = fmaf(2.0f * kyy, yc, ky);
                gy = fmaf(kzy, zc, gy); gy = fmaf(kxy, xc, gy);
                float margin = fmaf(fabsf(gz), hz,
                               fmaf(fabsf(gx), hx, fabsf(gy) * hy));
                pred = (qc + margin > QCUT);
            }
            u64 m = __ballot(pred);
            int rank = __popcll(m & ((1ull << lane) - 1ull));
            if (pred) list[qw][cnt + rank] = (u32)(n * 48);  // byte offset
            cnt += __popcll(m);
        }
        if (lane == 0) wcnt[qw] = cnt;
    }
    __syncthreads();

    // ---- phase 2: barrier-free accumulation over survivors ----
    float aA[4] = {0.f, 0.f, 0.f, 0.f};
    float aB[4] = {0.f, 0.f, 0.f, 0.f};
    const char* cfb = (const char*)cft;

#pragma unroll
    for (int seg = 0; seg < 4; ++seg) {
        const int cnt = wcnt[seg];
#pragma unroll 2
        for (int j = qw; j < cnt; j += 4) {
            u32 off = list[seg][j];                      // LDS broadcast
            const float4* cf = (const float4*)(cfb + off);
            float4 w0 = cf[0];   // k0, kz, kx, ky
            float4 w1 = cf[1];   // kzz, kxx, kyy, kzx
            float4 w2 = cf[2];   // kzy, kxy, dA, dB

            float bb = fmaf(w0.y, z, w0.x);
            bb = fmaf(w1.x, zz, bb);
            bb = fmaf(w0.z, x, bb);
            bb = fmaf(w1.y, xx, bb);
            bb = fmaf(w1.w, zx, bb);
            float cy = fmaf(w2.x, z, w0.w);
            cy = fmaf(w2.y, x, cy);

#pragma unroll
            for (int i = 0; i < 4; ++i) {
                float qv = fmaf(w1.z, yy[i], fmaf(cy, y[i], bb));
                float r = exp2_fast(qv);
                aA[i] = fmaf(r, w2.z, aA[i]);
                aB[i] = fmaf(r, w2.w, aB[i]);
            }
        }
    }

    // ---- combine 4 waves through LDS ----
#pragma unroll
    for (int i = 0; i < 4; ++i) {
        cbuf[qw][s][i][0] = aA[i];
        cbuf[qw][s][i][1] = aB[i];
    }
    __syncthreads();

    const int s2 = t >> 2, i2 = t & 3;
    float A = cbuf[0][s2][i2][0] + cbuf[1][s2][i2][0]
            + cbuf[2][s2][i2][0] + cbuf[3][s2][i2][0];
    float B = cbuf[0][s2][i2][1] + cbuf[1][s2][i2][1]
            + cbuf[2][s2][i2][1] + cbuf[3][s2][i2][1];
    const int dz2 = s2 >> 4, dx2 = (s2 >> 1) & 7, dyq2 = s2 & 1;
    const int iz2 = bz * 4 + dz2, ix2 = bx * 8 + dx2;
    const int iy2 = by * 8 + dyq2 * 4 + i2;
    out[(iz2 * 64 + ix2) * 64 + iy2] = (u32)f2bf(B) | ((u32)f2bf(A) << 16);
}

// ---------------- fallback (r9 kernel, no workspace) ---------------------
constexpr int CHUNK = 256;

__global__ __launch_bounds__(256, 4) void vox_fallback(
    const float* __restrict__ pos, const float* __restrict__ cov,
    const float* __restrict__ dA,  const float* __restrict__ dB,
    u32* __restrict__ out, int N)
{
    __shared__ float4 sg[CHUNK * 3];
    __shared__ float  cbuf[4][64][4][2];
    __shared__ int    wcnt[4];

    const int t = threadIdx.x, qw = t >> 6, lane = t & 63, s = lane;
    const int b = blockIdx.x;
    const int bz = b >> 6, bx = (b >> 3) & 7, by = b & 7;
    const int dz = s >> 4, dx = (s >> 1) & 7, dyq = s & 1;
    const int iz = bz * 4 + dz, ix = bx * 8 + dx, iy0 = by * 8 + dyq * 4;

    const float step = 2.0f / 63.0f;
    const float z = -1.0f + step * (float)iz;
    const float x = -1.0f + step * (float)ix;
    const float zz = z * z, xx = x * x, zx = z * x;
    float y[4], yy[4];
#pragma unroll
    for (int i = 0; i < 4; ++i) {
        y[i] = -1.0f + step * (float)(iy0 + i);
        yy[i] = y[i] * y[i];
    }
    const float zc = -1.0f + step * ((float)(bz * 4) + 1.5f);
    const float xc = -1.0f + step * ((float)(bx * 8) + 3.5f);
    const float yc = -1.0f + step * ((float)(by * 8) + 3.5f);
    const float hz = 1.5f * step, hx = 3.5f * step, hy = 3.5f * step;

    float aA[4] = {0.f, 0.f, 0.f, 0.f};
    float aB[4] = {0.f, 0.f, 0.f, 0.f};

    for (int cb = 0; cb < N; cb += CHUNK) {
        int n = cb + t;
        bool pred = false;
        float4 F0, F1, F2;
        if (n < N) {
            const float sc = -0.7213475204444817f;
            float p0 = pos[3 * n + 0], p1 = pos[3 * n + 1], p2 = pos[3 * n + 2];
            const float* c = cov + 9 * n;
            float c00 = c[0], c01 = c[1], c02 = c[2];
            float c10 = c[3], c11 = c[4], c12 = c[5];
            float c20 = c[6], c21 = c[7], c22 = c[8];
            float s01 = c01 + c10, s02 = c02 + c20, s12 = c12 + c21;
            float k0 = sc * (c00 * p0 * p0 + c11 * p1 * p1 + c22 * p2 * p2
                             + s01 * p0 * p1 + s02 * p0 * p2 + s12 * p1 * p2);
            float kz = -sc * (2.0f * c00 * p0 + s01 * p1 + s02 * p2);
            float kx = -sc * (s01 * p0 + 2.0f * c11 * p1 + s12 * p2);
            float ky = -sc * (s02 * p0 + s12 * p1 + 2.0f * c22 * p2);
            float kzz = sc * c00, kxx = sc * c11, kyy = sc * c22;
            float kzx = sc * s01, kzy = sc * s02, kxy = sc * s12;
            F0 = make_float4(k0, kz, kx, ky);
            F1 = make_float4(kzz, kxx, kyy, kzx);
            F2 = make_float4(kzy, kxy, dA[n], dB[n]);
            float bc = fmaf(kz, zc, k0);
            bc = fmaf(kzz, zc * zc, bc);
            bc = fmaf(kx, xc, bc);
            bc = fmaf(kxx, xc * xc, bc);
            bc = fmaf(kzx, zc * xc, bc);
            float cyc_ = fmaf(kzy, zc, ky);
            cyc_ = fmaf(kxy, xc, cyc_);
            float qc = fmaf(kyy, yc * yc, fmaf(cyc_, yc, bc));
            float gz = fmaf(2.0f * kzz, zc, kz);
            gz = fmaf(kzx, xc, gz); gz = fmaf(kzy, yc, gz);
            float gx = fmaf(2.0f * kxx, xc, kx);
            gx = fmaf(kzx, zc, gx); gx = fmaf(kxy, yc, gx);
            float gy = fmaf(2.0f * kyy, yc, ky);
            gy = fmaf(kzy, zc, gy); gy = fmaf(kxy, xc, gy);
            float margin = fmaf(fabsf(gz), hz, fmaf(fabsf(gx), hx, fabsf(gy) * hy));
            pred = (qc + margin > QCUT);
        }
        u64 mask = __ballot(pred);
        int rank = __popcll(mask & ((1ull << lane) - 1ull));
        if (lane == 0) wcnt[qw] = __popcll(mask);
        __syncthreads();
        int off = 0;
#pragma unroll
        for (int w = 0; w < 4; ++w) if (w < qw) off += wcnt[w];
        const int total = wcnt[0] + wcnt[1] + wcnt[2] + wcnt[3];
        if (pred) {
            int p = off + rank;
            sg[3 * p + 0] = F0; sg[3 * p + 1] = F1; sg[3 * p + 2] = F2;
        }
        __syncthreads();
#pragma unroll 2
        for (int j = qw; j < total; j += 4) {
            float4 w0 = sg[3 * j + 0], w1 = sg[3 * j + 1], w2 = sg[3 * j + 2];
            float bb = fmaf(w0.y, z, w0.x);
            bb = fmaf(w1.x, zz, bb);
            bb = fmaf(w0.z, x, bb);
            bb = fmaf(w1.y, xx, bb);
            bb = fmaf(w1.w, zx, bb);
            float cy = fmaf(w2.x, z, w0.w);
            cy = fmaf(w2.y, x, cy);
#pragma unroll
            for (int i = 0; i < 4; ++i) {
                float qv = fmaf(w1.z, yy[i], fmaf(cy, y[i], bb));
                float r = exp2_fast(qv);
                aA[i] = fmaf(r, w2.z, aA[i]);
                aB[i] = fmaf(r, w2.w, aB[i]);
            }
        }
        __syncthreads();
    }
#pragma unroll
    for (int i = 0; i < 4; ++i) {
        cbuf[qw][s][i][0] = aA[i];
        cbuf[qw][s][i][1] = aB[i];
    }
    __syncthreads();
    const int s2 = t >> 2, i2 = t & 3;
    float A = cbuf[0][s2][i2][0] + cbuf[1][s2][i2][0]
            + cbuf[2][s2][i2][0] + cbuf[3][s2][i2][0];
    float B = cbuf[0][s2][i2][1] + cbuf[1][s2][i2][1]
            + cbuf[2][s2][i2][1] + cbuf[3][s2][i2][1];
    const int dz2 = s2 >> 4, dx2 = (s2 >> 1) & 7, dyq2 = s2 & 1;
    const int iz2 = bz * 4 + dz2, ix2 = bx * 8 + dx2;
    const int iy2 = by * 8 + dyq2 * 4 + i2;
    out[(iz2 * 64 + ix2) * 64 + iy2] = (u32)f2bf(B) | ((u32)f2bf(A) << 16);
}

extern "C" void kernel_launch(void* const* d_in, const int* in_sizes, int n_in,
                              void* d_out, int out_size, void* d_ws, size_t ws_size,
                              hipStream_t stream)
{
    const float* pos = (const float*)d_in[0];
    const float* cov = (const float*)d_in[1];
    const float* dA  = (const float*)d_in[2];
    const float* dB  = (const float*)d_in[3];
    const int N = in_sizes[0] / 3;          // 4096

    if (N == 4096 && ws_size >= (size_t)N * 48) {
        float4* cft = (float4*)d_ws;
        vox_prep<<<(N + 255) / 256, 256, 0, stream>>>(pos, cov, dA, dB, cft, N);
        vox_main<<<1024, 256, 0, stream>>>(cft, (u32*)d_out, N);
    } else {
        vox_fallback<<<1024, 256, 0, stream>>>(pos, cov, dA, dB, (u32*)d_out, N);
    }
}

// Round 11
// 97.376 us; speedup vs baseline: 1.4936x; 1.4936x over previous
//
#include <hip/hip_runtime.h>

// Voxelizer: V = 64^3 voxels over [-1,1]^3, N = 4096 anisotropic Gaussians.
// out[v] = packed bf16 pair: low16 = sum(resp*dB), high16 = sum(resp*dA),
//   resp = exp2(q), q = degree-2 poly in voxel coords (-0.5*log2(e) folded in).
//
// Layout (established r0-r10, PASSING since r6):
//   d_in : fp32. [0] pos [N,3], [1] cov [N,3,3], [2] dA, [3] dB
//   d_out: 524288 bf16 = u32 per voxel (low=dB-sum, high=dA-sum)
//
// r10 post-mortem: global-load inner loop -> latency-bound (VALUBusy 37%).
// r11: LDS-resident inner loop (r9) + d_ws coefficient table staging (cheap
//      copy) + register prefetch of next chunk + 512-chunks with per-wave
//      segmented compaction => 16 barriers/block (r9: 48), loads fully hidden.

#ifndef __has_builtin
#define __has_builtin(x) 0
#endif

using u16 = unsigned short;
using u32 = unsigned int;
using u64 = unsigned long long;

__device__ __forceinline__ u16 f2bf(float f) {   // fp32 -> bf16, RNE
    u32 x = __float_as_uint(f);
    x += 0x7FFFu + ((x >> 16) & 1u);
    return (u16)(x >> 16);
}

__device__ __forceinline__ float exp2_fast(float x) {
#if __has_builtin(__builtin_amdgcn_exp2f)
    return __builtin_amdgcn_exp2f(x);            // v_exp_f32
#else
    return exp2f(x);
#endif
}

constexpr float QCUT = -18.0f;       // drop pairs with resp < 2^-18
constexpr int   SEGCAP = 128;        // per-wave survivors per 512-chunk

// conservative reachability: q concave => q(v) <= q(center) + sum |grad_i|*h_i
__device__ __forceinline__ bool btest(float4 F0, float4 F1, float4 F2,
                                      float zc, float xc, float yc,
                                      float hz, float hx, float hy)
{
    float k0 = F0.x, kz = F0.y, kx = F0.z, ky = F0.w;
    float kzz = F1.x, kxx = F1.y, kyy = F1.z, kzx = F1.w;
    float kzy = F2.x, kxy = F2.y;
    float bc = fmaf(kz, zc, k0);
    bc = fmaf(kzz, zc * zc, bc);
    bc = fmaf(kx, xc, bc);
    bc = fmaf(kxx, xc * xc, bc);
    bc = fmaf(kzx, zc * xc, bc);
    float cy0 = fmaf(kzy, zc, ky);
    cy0 = fmaf(kxy, xc, cy0);
    float qc = fmaf(kyy, yc * yc, fmaf(cy0, yc, bc));
    float gz = fmaf(2.0f * kzz, zc, kz);
    gz = fmaf(kzx, xc, gz); gz = fmaf(kzy, yc, gz);
    float gx = fmaf(2.0f * kxx, xc, kx);
    gx = fmaf(kzx, zc, gx); gx = fmaf(kxy, yc, gx);
    float gy = fmaf(2.0f * kyy, yc, ky);
    gy = fmaf(kzy, zc, gy); gy = fmaf(kxy, xc, gy);
    float margin = fmaf(fabsf(gz), hz, fmaf(fabsf(gx), hx, fabsf(gy) * hy));
    return (qc + margin > QCUT);
}

// ---------------- prepass: per-gaussian polynomial coefficients ----------
__global__ __launch_bounds__(256) void vox_prep(
    const float* __restrict__ pos, const float* __restrict__ cov,
    const float* __restrict__ dA,  const float* __restrict__ dB,
    float4* __restrict__ cft, int N)
{
    int n = blockIdx.x * 256 + threadIdx.x;
    if (n >= N) return;
    const float sc = -0.7213475204444817f;   // -0.5 * log2(e)
    float p0 = pos[3 * n + 0], p1 = pos[3 * n + 1], p2 = pos[3 * n + 2];
    const float* c = cov + 9 * n;
    float c00 = c[0], c01 = c[1], c02 = c[2];
    float c10 = c[3], c11 = c[4], c12 = c[5];
    float c20 = c[6], c21 = c[7], c22 = c[8];
    float s01 = c01 + c10, s02 = c02 + c20, s12 = c12 + c21;
    float k0 = sc * (c00 * p0 * p0 + c11 * p1 * p1 + c22 * p2 * p2
                     + s01 * p0 * p1 + s02 * p0 * p2 + s12 * p1 * p2);
    float kz = -sc * (2.0f * c00 * p0 + s01 * p1 + s02 * p2);
    float kx = -sc * (s01 * p0 + 2.0f * c11 * p1 + s12 * p2);
    float ky = -sc * (s02 * p0 + s12 * p1 + 2.0f * c22 * p2);
    cft[3 * n + 0] = make_float4(k0, kz, kx, ky);
    cft[3 * n + 1] = make_float4(sc * c00, sc * c11, sc * c22, sc * s01);
    cft[3 * n + 2] = make_float4(sc * s02, sc * s12, dA[n], dB[n]);
}

// ---------------- main: brick = 4(z) x 8(x) x 8(y) voxels ----------------
// 1024 blocks x 256 threads (4 waves). Per 512-gaussian chunk: wave qw tests
// its 128 (2/lane, coefficients prefetched into regs), compacts into its OWN
// LDS segment (no cross-wave prefix), 1 barrier, prefetches next chunk,
// accumulates over all 4 segments stride-4 from LDS, 1 barrier.
__global__ __launch_bounds__(256, 4) void vox_main(
    const float4* __restrict__ cft,  // [N*3] coefficient table (d_ws)
    u32* __restrict__ out)           // [VTOT] packed (dB | dA<<16)
{
    __shared__ float4 sgl[4 * SEGCAP * 3];   // 24 KB compacted coefficients
    __shared__ int    wc[4];
    __shared__ float  cbuf[4][64][4][2];     // 8 KB combine

    const int t    = threadIdx.x;
    const int qw   = t >> 6;
    const int lane = t & 63;
    const int b    = (blockIdx.x * 331) & 1023;  // scattered brick mapping
    const int bz = b >> 6, bx = (b >> 3) & 7, by = b & 7;

    const int s = lane;
    const int dz = s >> 4, dx = (s >> 1) & 7, dyq = s & 1;
    const int iz = bz * 4 + dz, ix = bx * 8 + dx, iy0 = by * 8 + dyq * 4;

    const float step = 2.0f / 63.0f;
    const float z = -1.0f + step * (float)iz;
    const float x = -1.0f + step * (float)ix;
    const float zz = z * z, xx = x * x, zx = z * x;
    float y[4], yy[4];
#pragma unroll
    for (int i = 0; i < 4; ++i) {
        y[i] = -1.0f + step * (float)(iy0 + i);
        yy[i] = y[i] * y[i];
    }

    const float zc = -1.0f + step * ((float)(bz * 4) + 1.5f);
    const float xc = -1.0f + step * ((float)(bx * 8) + 3.5f);
    const float yc = -1.0f + step * ((float)(by * 8) + 3.5f);
    const float hz = 1.5f * step, hx = 3.5f * step, hy = 3.5f * step;

    const u64 lmask = (1ull << lane) - 1ull;

    // ---- prefetch chunk 0 (2 gaussians per thread) ----
    int n0 = qw * 128 + lane;
    float4 g0a = cft[3 * n0 + 0], g0b = cft[3 * n0 + 1], g0c = cft[3 * n0 + 2];
    float4 g1a = cft[3 * (n0 + 64) + 0], g1b = cft[3 * (n0 + 64) + 1],
           g1c = cft[3 * (n0 + 64) + 2];

    float aA[4] = {0.f, 0.f, 0.f, 0.f};
    float aB[4] = {0.f, 0.f, 0.f, 0.f};

    for (int cb = 0; cb < 8; ++cb) {
        // ---- test + compact current regs into segment qw ----
        bool p0 = btest(g0a, g0b, g0c, zc, xc, yc, hz, hx, hy);
        bool p1 = btest(g1a, g1b, g1c, zc, xc, yc, hz, hx, hy);
        u64 m0 = __ballot(p0);
        u64 m1 = __ballot(p1);
        int r0 = __popcll(m0 & lmask);
        int c0 = __popcll(m0);
        int r1 = c0 + __popcll(m1 & lmask);
        int c1 = c0 + __popcll(m1);
        float4* segp = &sgl[qw * SEGCAP * 3];
        if (p0) { segp[3 * r0 + 0] = g0a; segp[3 * r0 + 1] = g0b; segp[3 * r0 + 2] = g0c; }
        if (p1) { segp[3 * r1 + 0] = g1a; segp[3 * r1 + 1] = g1b; segp[3 * r1 + 2] = g1c; }
        if (lane == 0) wc[qw] = c1;
        __syncthreads();

        // ---- prefetch next chunk (hidden under the inner loop) ----
        if (cb < 7) {
            int nn = (cb + 1) * 512 + qw * 128 + lane;
            g0a = cft[3 * nn + 0]; g0b = cft[3 * nn + 1]; g0c = cft[3 * nn + 2];
            g1a = cft[3 * (nn + 64) + 0]; g1b = cft[3 * (nn + 64) + 1];
            g1c = cft[3 * (nn + 64) + 2];
        }

        int cnt0 = wc[0], cnt1 = wc[1], cnt2 = wc[2], cnt3 = wc[3];
        int cnts[4] = {cnt0, cnt1, cnt2, cnt3};

        // ---- accumulate over survivors (LDS broadcast reads) ----
#pragma unroll
        for (int seg = 0; seg < 4; ++seg) {
            const float4* sp = &sgl[seg * SEGCAP * 3];
            const int cnt = cnts[seg];
#pragma unroll 2
            for (int j = qw; j < cnt; j += 4) {
                float4 w0 = sp[3 * j + 0];   // k0, kz, kx, ky
                float4 w1 = sp[3 * j + 1];   // kzz, kxx, kyy, kzx
                float4 w2 = sp[3 * j + 2];   // kzy, kxy, dA, dB

                float bb = fmaf(w0.y, z, w0.x);
                bb = fmaf(w1.x, zz, bb);
                bb = fmaf(w0.z, x, bb);
                bb = fmaf(w1.y, xx, bb);
                bb = fmaf(w1.w, zx, bb);
                float cy = fmaf(w2.x, z, w0.w);
                cy = fmaf(w2.y, x, cy);

#pragma unroll
                for (int i = 0; i < 4; ++i) {
                    float qv = fmaf(w1.z, yy[i], fmaf(cy, y[i], bb));
                    float r = exp2_fast(qv);
                    aA[i] = fmaf(r, w2.z, aA[i]);
                    aB[i] = fmaf(r, w2.w, aB[i]);
                }
            }
        }
        __syncthreads();   // protect sgl before next chunk's compaction
    }

    // ---- combine 4 waves through LDS ----
#pragma unroll
    for (int i = 0; i < 4; ++i) {
        cbuf[qw][s][i][0] = aA[i];
        cbuf[qw][s][i][1] = aB[i];
    }
    __syncthreads();

    const int s2 = t >> 2, i2 = t & 3;
    float A = cbuf[0][s2][i2][0] + cbuf[1][s2][i2][0]
            + cbuf[2][s2][i2][0] + cbuf[3][s2][i2][0];
    float B = cbuf[0][s2][i2][1] + cbuf[1][s2][i2][1]
            + cbuf[2][s2][i2][1] + cbuf[3][s2][i2][1];
    const int dz2 = s2 >> 4, dx2 = (s2 >> 1) & 7, dyq2 = s2 & 1;
    const int iz2 = bz * 4 + dz2, ix2 = bx * 8 + dx2;
    const int iy2 = by * 8 + dyq2 * 4 + i2;
    out[(iz2 * 64 + ix2) * 64 + iy2] = (u32)f2bf(B) | ((u32)f2bf(A) << 16);
}

// ---------------- fallback (r9 kernel, no workspace) ---------------------
constexpr int CHUNK = 256;

__global__ __launch_bounds__(256, 4) void vox_fallback(
    const float* __restrict__ pos, const float* __restrict__ cov,
    const float* __restrict__ dA,  const float* __restrict__ dB,
    u32* __restrict__ out, int N)
{
    __shared__ float4 sg[CHUNK * 3];
    __shared__ float  cbuf[4][64][4][2];
    __shared__ int    wcnt[4];

    const int t = threadIdx.x, qw = t >> 6, lane = t & 63, s = lane;
    const int b = blockIdx.x;
    const int bz = b >> 6, bx = (b >> 3) & 7, by = b & 7;
    const int dz = s >> 4, dx = (s >> 1) & 7, dyq = s & 1;
    const int iz = bz * 4 + dz, ix = bx * 8 + dx, iy0 = by * 8 + dyq * 4;

    const float step = 2.0f / 63.0f;
    const float z = -1.0f + step * (float)iz;
    const float x = -1.0f + step * (float)ix;
    const float zz = z * z, xx = x * x, zx = z * x;
    float y[4], yy[4];
#pragma unroll
    for (int i = 0; i < 4; ++i) {
        y[i] = -1.0f + step * (float)(iy0 + i);
        yy[i] = y[i] * y[i];
    }
    const float zc = -1.0f + step * ((float)(bz * 4) + 1.5f);
    const float xc = -1.0f + step * ((float)(bx * 8) + 3.5f);
    const float yc = -1.0f + step * ((float)(by * 8) + 3.5f);
    const float hz = 1.5f * step, hx = 3.5f * step, hy = 3.5f * step;

    float aA[4] = {0.f, 0.f, 0.f, 0.f};
    float aB[4] = {0.f, 0.f, 0.f, 0.f};

    for (int cb = 0; cb < N; cb += CHUNK) {
        int n = cb + t;
        bool pred = false;
        float4 F0, F1, F2;
        if (n < N) {
            const float sc = -0.7213475204444817f;
            float p0 = pos[3 * n + 0], p1 = pos[3 * n + 1], p2 = pos[3 * n + 2];
            const float* c = cov + 9 * n;
            float c00 = c[0], c01 = c[1], c02 = c[2];
            float c10 = c[3], c11 = c[4], c12 = c[5];
            float c20 = c[6], c21 = c[7], c22 = c[8];
            float s01 = c01 + c10, s02 = c02 + c20, s12 = c12 + c21;
            float k0 = sc * (c00 * p0 * p0 + c11 * p1 * p1 + c22 * p2 * p2
                             + s01 * p0 * p1 + s02 * p0 * p2 + s12 * p1 * p2);
            float kz = -sc * (2.0f * c00 * p0 + s01 * p1 + s02 * p2);
            float kx = -sc * (s01 * p0 + 2.0f * c11 * p1 + s12 * p2);
            float ky = -sc * (s02 * p0 + s12 * p1 + 2.0f * c22 * p2);
            F0 = make_float4(k0, kz, kx, ky);
            F1 = make_float4(sc * c00, sc * c11, sc * c22, sc * s01);
            F2 = make_float4(sc * s02, sc * s12, dA[n], dB[n]);
            pred = btest(F0, F1, F2, zc, xc, yc, hz, hx, hy);
        }
        u64 mask = __ballot(pred);
        int rank = __popcll(mask & ((1ull << lane) - 1ull));
        if (lane == 0) wcnt[qw] = __popcll(mask);
        __syncthreads();
        int off = 0;
#pragma unroll
        for (int w = 0; w < 4; ++w) if (w < qw) off += wcnt[w];
        const int total = wcnt[0] + wcnt[1] + wcnt[2] + wcnt[3];
        if (pred) {
            int p = off + rank;
            sg[3 * p + 0] = F0; sg[3 * p + 1] = F1; sg[3 * p + 2] = F2;
        }
        __syncthreads();
#pragma unroll 2
        for (int j = qw; j < total; j += 4) {
            float4 w0 = sg[3 * j + 0], w1 = sg[3 * j + 1], w2 = sg[3 * j + 2];
            float bb = fmaf(w0.y, z, w0.x);
            bb = fmaf(w1.x, zz, bb);
            bb = fmaf(w0.z, x, bb);
            bb = fmaf(w1.y, xx, bb);
            bb = fmaf(w1.w, zx, bb);
            float cy = fmaf(w2.x, z, w0.w);
            cy = fmaf(w2.y, x, cy);
#pragma unroll
            for (int i = 0; i < 4; ++i) {
                float qv = fmaf(w1.z, yy[i], fmaf(cy, y[i], bb));
                float r = exp2_fast(qv);
                aA[i] = fmaf(r, w2.z, aA[i]);
                aB[i] = fmaf(r, w2.w, aB[i]);
            }
        }
        __syncthreads();
    }
#pragma unroll
    for (int i = 0; i < 4; ++i) {
        cbuf[qw][s][i][0] = aA[i];
        cbuf[qw][s][i][1] = aB[i];
    }
    __syncthreads();
    const int s2 = t >> 2, i2 = t & 3;
    float A = cbuf[0][s2][i2][0] + cbuf[1][s2][i2][0]
            + cbuf[2][s2][i2][0] + cbuf[3][s2][i2][0];
    float B = cbuf[0][s2][i2][1] + cbuf[1][s2][i2][1]
            + cbuf[2][s2][i2][1] + cbuf[3][s2][i2][1];
    const int dz2 = s2 >> 4, dx2 = (s2 >> 1) & 7, dyq2 = s2 & 1;
    const int iz2 = bz * 4 + dz2, ix2 = bx * 8 + dx2;
    const int iy2 = by * 8 + dyq2 * 4 + i2;
    out[(iz2 * 64 + ix2) * 64 + iy2] = (u32)f2bf(B) | ((u32)f2bf(A) << 16);
}

extern "C" void kernel_launch(void* const* d_in, const int* in_sizes, int n_in,
                              void* d_out, int out_size, void* d_ws, size_t ws_size,
                              hipStream_t stream)
{
    const float* pos = (const float*)d_in[0];
    const float* cov = (const float*)d_in[1];
    const float* dA  = (const float*)d_in[2];
    const float* dB  = (const float*)d_in[3];
    const int N = in_sizes[0] / 3;          // 4096

    if (N == 4096 && ws_size >= (size_t)N * 48) {
        float4* cft = (float4*)d_ws;
        vox_prep<<<(N + 255) / 256, 256, 0, stream>>>(pos, cov, dA, dB, cft, N);
        vox_main<<<1024, 256, 0, stream>>>(cft, (u32*)d_out);
    } else {
        vox_fallback<<<1024, 256, 0, stream>>>(pos, cov, dA, dB, (u32*)d_out, N);
    }
}

// Round 12
// 82.952 us; speedup vs baseline: 1.7533x; 1.1739x over previous
//
#include <hip/hip_runtime.h>

// Voxelizer: V = 64^3 voxels over [-1,1]^3, N = 4096 anisotropic Gaussians.
// out[v] = packed bf16 pair: low16 = sum(resp*dB), high16 = sum(resp*dA),
//   resp = exp2(q), q = degree-2 poly in voxel coords (-0.5*log2(e) folded in).
//
// Layout (established r0-r11, PASSING since r6):
//   d_in : fp32. [0] pos [N,3], [1] cov [N,3,3], [2] dA, [3] dB
//   d_out: 524288 bf16 = u32 per voxel (low=dB-sum, high=dA-sum)
//
// r11 post-mortem: 97us, VALUBusy 56% -- static 4 blocks/CU (33KB LDS), no
// backfill; brick imbalance + 16 lockstep barriers = 43% idle.
// r12: (brick, gaussian-half) work split -> 2048 blocks writing disjoint f32
//      partials to d_ws (no atomics) + pack kernel; LDS 20.5KB -> 7 blocks/CU
//      capacity -> backfill; center-out (LPT) brick order. Inner loop = r11.

#ifndef __has_builtin
#define __has_builtin(x) 0
#endif

using u16 = unsigned short;
using u32 = unsigned int;
using u64 = unsigned long long;

constexpr int   VTOT = 64 * 64 * 64;
constexpr float QCUT = -18.0f;       // drop pairs with resp < 2^-18

__device__ __forceinline__ u16 f2bf(float f) {   // fp32 -> bf16, RNE
    u32 x = __float_as_uint(f);
    x += 0x7FFFu + ((x >> 16) & 1u);
    return (u16)(x >> 16);
}

__device__ __forceinline__ float exp2_fast(float x) {
#if __has_builtin(__builtin_amdgcn_exp2f)
    return __builtin_amdgcn_exp2f(x);            // v_exp_f32
#else
    return exp2f(x);
#endif
}

// conservative reachability: q concave => q(v) <= q(center) + sum |grad_i|*h_i
__device__ __forceinline__ bool btest(float4 F0, float4 F1, float4 F2,
                                      float zc, float xc, float yc,
                                      float hz, float hx, float hy)
{
    float k0 = F0.x, kz = F0.y, kx = F0.z, ky = F0.w;
    float kzz = F1.x, kxx = F1.y, kyy = F1.z, kzx = F1.w;
    float kzy = F2.x, kxy = F2.y;
    float bc = fmaf(kz, zc, k0);
    bc = fmaf(kzz, zc * zc, bc);
    bc = fmaf(kx, xc, bc);
    bc = fmaf(kxx, xc * xc, bc);
    bc = fmaf(kzx, zc * xc, bc);
    float cy0 = fmaf(kzy, zc, ky);
    cy0 = fmaf(kxy, xc, cy0);
    float qc = fmaf(kyy, yc * yc, fmaf(cy0, yc, bc));
    float gz = fmaf(2.0f * kzz, zc, kz);
    gz = fmaf(kzx, xc, gz); gz = fmaf(kzy, yc, gz);
    float gx = fmaf(2.0f * kxx, xc, kx);
    gx = fmaf(kzx, zc, gx); gx = fmaf(kxy, yc, gx);
    float gy = fmaf(2.0f * kyy, yc, ky);
    gy = fmaf(kzy, zc, gy); gy = fmaf(kxy, xc, gy);
    float margin = fmaf(fabsf(gz), hz, fmaf(fabsf(gx), hx, fabsf(gy) * hy));
    return (qc + margin > QCUT);
}

// ---------------- prepass: per-gaussian polynomial coefficients ----------
__global__ __launch_bounds__(256) void vox_prep(
    const float* __restrict__ pos, const float* __restrict__ cov,
    const float* __restrict__ dA,  const float* __restrict__ dB,
    float4* __restrict__ cft, int N)
{
    int n = blockIdx.x * 256 + threadIdx.x;
    if (n >= N) return;
    const float sc = -0.7213475204444817f;   // -0.5 * log2(e)
    float p0 = pos[3 * n + 0], p1 = pos[3 * n + 1], p2 = pos[3 * n + 2];
    const float* c = cov + 9 * n;
    float c00 = c[0], c01 = c[1], c02 = c[2];
    float c10 = c[3], c11 = c[4], c12 = c[5];
    float c20 = c[6], c21 = c[7], c22 = c[8];
    float s01 = c01 + c10, s02 = c02 + c20, s12 = c12 + c21;
    float k0 = sc * (c00 * p0 * p0 + c11 * p1 * p1 + c22 * p2 * p2
                     + s01 * p0 * p1 + s02 * p0 * p2 + s12 * p1 * p2);
    float kz = -sc * (2.0f * c00 * p0 + s01 * p1 + s02 * p2);
    float kx = -sc * (s01 * p0 + 2.0f * c11 * p1 + s12 * p2);
    float ky = -sc * (s02 * p0 + s12 * p1 + 2.0f * c22 * p2);
    cft[3 * n + 0] = make_float4(k0, kz, kx, ky);
    cft[3 * n + 1] = make_float4(sc * c00, sc * c11, sc * c22, sc * s01);
    cft[3 * n + 2] = make_float4(sc * s02, sc * s12, dA[n], dB[n]);
}

// ---------------- accum: (brick, gaussian-half) blocks -------------------
// 2048 blocks x 256 threads (4 waves). Block w: half h=w&1 (2048 gaussians),
// brick bi=w>>1 mapped CENTER-OUT (dense bricks first => LPT scheduling).
// Per 256-gaussian chunk: 1 btest/thread (regs prefetched), wave-segmented
// compaction into own LDS segment, barrier, prefetch next, accumulate over
// 4 segments stride-4 from LDS, barrier. Partial f32 sums -> pws (disjoint).
__global__ __launch_bounds__(256, 4) void vox_accum(
    const float4* __restrict__ cft,  // [N*3] coefficient table
    float2* __restrict__ pws)        // [2*VTOT] (A,B) partials per half
{
    __shared__ float4 sgl[4 * 64 * 3];       // 12 KB compacted coefficients
    __shared__ int    wc[4];
    __shared__ float  cbuf[4][64][4][2];     // 8 KB combine

    const int t    = threadIdx.x;
    const int qw   = t >> 6;
    const int lane = t & 63;
    const int w    = blockIdx.x;
    const int h    = w & 1;
    const int bi   = w >> 1;
    // center-out brick mapping (bz in 0..15 quad-slabs, bx/by in 0..7)
    const int i16 = bi >> 6, i8x = (bi >> 3) & 7, i8y = bi & 7;
    const int bz = (i16 & 1) ? 8 + (i16 >> 1) : 7 - (i16 >> 1);
    const int bx = (i8x & 1) ? 4 + (i8x >> 1) : 3 - (i8x >> 1);
    const int by = (i8y & 1) ? 4 + (i8y >> 1) : 3 - (i8y >> 1);

    const int s = lane;
    const int dz = s >> 4, dx = (s >> 1) & 7, dyq = s & 1;
    const int iz = bz * 4 + dz, ix = bx * 8 + dx, iy0 = by * 8 + dyq * 4;

    const float step = 2.0f / 63.0f;
    const float z = -1.0f + step * (float)iz;
    const float x = -1.0f + step * (float)ix;
    const float zz = z * z, xx = x * x, zx = z * x;
    float y[4], yy[4];
#pragma unroll
    for (int i = 0; i < 4; ++i) {
        y[i] = -1.0f + step * (float)(iy0 + i);
        yy[i] = y[i] * y[i];
    }

    const float zc = -1.0f + step * ((float)(bz * 4) + 1.5f);
    const float xc = -1.0f + step * ((float)(bx * 8) + 3.5f);
    const float yc = -1.0f + step * ((float)(by * 8) + 3.5f);
    const float hz = 1.5f * step, hx = 3.5f * step, hy = 3.5f * step;

    const u64 lmask = (1ull << lane) - 1ull;
    const int gbase = h * 2048;

    // prefetch chunk 0 (1 gaussian per thread)
    int n0 = gbase + qw * 64 + lane;
    float4 ga = cft[3 * n0 + 0], gb = cft[3 * n0 + 1], gc = cft[3 * n0 + 2];

    float aA[4] = {0.f, 0.f, 0.f, 0.f};
    float aB[4] = {0.f, 0.f, 0.f, 0.f};

    for (int cb = 0; cb < 8; ++cb) {
        // ---- test + compact current regs into segment qw ----
        bool p = btest(ga, gb, gc, zc, xc, yc, hz, hx, hy);
        u64 m = __ballot(p);
        int r = __popcll(m & lmask);
        float4* segp = &sgl[qw * 64 * 3];
        if (p) { segp[3 * r + 0] = ga; segp[3 * r + 1] = gb; segp[3 * r + 2] = gc; }
        if (lane == 0) wc[qw] = __popcll(m);
        __syncthreads();

        // ---- prefetch next chunk (hidden under the inner loop) ----
        if (cb < 7) {
            int nn = gbase + (cb + 1) * 256 + qw * 64 + lane;
            ga = cft[3 * nn + 0]; gb = cft[3 * nn + 1]; gc = cft[3 * nn + 2];
        }

        int cnts[4] = {wc[0], wc[1], wc[2], wc[3]};

        // ---- accumulate over survivors (LDS broadcast reads) ----
#pragma unroll
        for (int seg = 0; seg < 4; ++seg) {
            const float4* sp = &sgl[seg * 64 * 3];
            const int cnt = cnts[seg];
#pragma unroll 2
            for (int j = qw; j < cnt; j += 4) {
                float4 w0 = sp[3 * j + 0];   // k0, kz, kx, ky
                float4 w1 = sp[3 * j + 1];   // kzz, kxx, kyy, kzx
                float4 w2 = sp[3 * j + 2];   // kzy, kxy, dA, dB

                float bb = fmaf(w0.y, z, w0.x);
                bb = fmaf(w1.x, zz, bb);
                bb = fmaf(w0.z, x, bb);
                bb = fmaf(w1.y, xx, bb);
                bb = fmaf(w1.w, zx, bb);
                float cy = fmaf(w2.x, z, w0.w);
                cy = fmaf(w2.y, x, cy);

#pragma unroll
                for (int i = 0; i < 4; ++i) {
                    float qv = fmaf(w1.z, yy[i], fmaf(cy, y[i], bb));
                    float rr = exp2_fast(qv);
                    aA[i] = fmaf(rr, w2.z, aA[i]);
                    aB[i] = fmaf(rr, w2.w, aB[i]);
                }
            }
        }
        __syncthreads();   // protect sgl before next chunk's compaction
    }

    // ---- combine 4 waves through LDS, write f32 partials ----
#pragma unroll
    for (int i = 0; i < 4; ++i) {
        cbuf[qw][s][i][0] = aA[i];
        cbuf[qw][s][i][1] = aB[i];
    }
    __syncthreads();

    const int s2 = t >> 2, i2 = t & 3;
    float A = cbuf[0][s2][i2][0] + cbuf[1][s2][i2][0]
            + cbuf[2][s2][i2][0] + cbuf[3][s2][i2][0];
    float B = cbuf[0][s2][i2][1] + cbuf[1][s2][i2][1]
            + cbuf[2][s2][i2][1] + cbuf[3][s2][i2][1];
    const int dz2 = s2 >> 4, dx2 = (s2 >> 1) & 7, dyq2 = s2 & 1;
    const int iz2 = bz * 4 + dz2, ix2 = bx * 8 + dx2;
    const int iy2 = by * 8 + dyq2 * 4 + i2;
    pws[h * VTOT + (iz2 * 64 + ix2) * 64 + iy2] = make_float2(A, B);
}

// ---------------- pack: sum halves, convert to bf16 ----------------------
__global__ __launch_bounds__(256) void vox_pack(
    const float2* __restrict__ pws, u32* __restrict__ out)
{
    int v2 = blockIdx.x * 256 + threadIdx.x;     // 2 voxels per thread
    const float4* p0 = (const float4*)pws;               // half 0
    const float4* p1 = (const float4*)(pws + VTOT);      // half 1
    float4 a = p0[v2], b = p1[v2];   // (A0,B0,A1,B1)
    float A0 = a.x + b.x, B0 = a.y + b.y;
    float A1 = a.z + b.z, B1 = a.w + b.w;
    uint2 o;
    o.x = (u32)f2bf(B0) | ((u32)f2bf(A0) << 16);
    o.y = (u32)f2bf(B1) | ((u32)f2bf(A1) << 16);
    *(uint2*)(out + 2 * v2) = o;
}

// ---------------- r11 main (mid-tier ws fallback) ------------------------
constexpr int SEGCAP = 128;

__global__ __launch_bounds__(256, 4) void vox_main(
    const float4* __restrict__ cft, u32* __restrict__ out)
{
    __shared__ float4 sgl[4 * SEGCAP * 3];
    __shared__ int    wc[4];
    __shared__ float  cbuf[4][64][4][2];

    const int t = threadIdx.x, qw = t >> 6, lane = t & 63;
    const int b = (blockIdx.x * 331) & 1023;
    const int bz = b >> 6, bx = (b >> 3) & 7, by = b & 7;
    const int s = lane;
    const int dz = s >> 4, dx = (s >> 1) & 7, dyq = s & 1;
    const int iz = bz * 4 + dz, ix = bx * 8 + dx, iy0 = by * 8 + dyq * 4;

    const float step = 2.0f / 63.0f;
    const float z = -1.0f + step * (float)iz;
    const float x = -1.0f + step * (float)ix;
    const float zz = z * z, xx = x * x, zx = z * x;
    float y[4], yy[4];
#pragma unroll
    for (int i = 0; i < 4; ++i) {
        y[i] = -1.0f + step * (float)(iy0 + i);
        yy[i] = y[i] * y[i];
    }
    const float zc = -1.0f + step * ((float)(bz * 4) + 1.5f);
    const float xc = -1.0f + step * ((float)(bx * 8) + 3.5f);
    const float yc = -1.0f + step * ((float)(by * 8) + 3.5f);
    const float hz = 1.5f * step, hx = 3.5f * step, hy = 3.5f * step;
    const u64 lmask = (1ull << lane) - 1ull;

    int n0 = qw * 128 + lane;
    float4 g0a = cft[3 * n0 + 0], g0b = cft[3 * n0 + 1], g0c = cft[3 * n0 + 2];
    float4 g1a = cft[3 * (n0 + 64) + 0], g1b = cft[3 * (n0 + 64) + 1],
           g1c = cft[3 * (n0 + 64) + 2];

    float aA[4] = {0.f, 0.f, 0.f, 0.f};
    float aB[4] = {0.f, 0.f, 0.f, 0.f};

    for (int cb = 0; cb < 8; ++cb) {
        bool p0 = btest(g0a, g0b, g0c, zc, xc, yc, hz, hx, hy);
        bool p1 = btest(g1a, g1b, g1c, zc, xc, yc, hz, hx, hy);
        u64 m0 = __ballot(p0);
        u64 m1 = __ballot(p1);
        int r0 = __popcll(m0 & lmask);
        int c0 = __popcll(m0);
        int r1 = c0 + __popcll(m1 & lmask);
        int c1 = c0 + __popcll(m1);
        float4* segp = &sgl[qw * SEGCAP * 3];
        if (p0) { segp[3 * r0 + 0] = g0a; segp[3 * r0 + 1] = g0b; segp[3 * r0 + 2] = g0c; }
        if (p1) { segp[3 * r1 + 0] = g1a; segp[3 * r1 + 1] = g1b; segp[3 * r1 + 2] = g1c; }
        if (lane == 0) wc[qw] = c1;
        __syncthreads();

        if (cb < 7) {
            int nn = (cb + 1) * 512 + qw * 128 + lane;
            g0a = cft[3 * nn + 0]; g0b = cft[3 * nn + 1]; g0c = cft[3 * nn + 2];
            g1a = cft[3 * (nn + 64) + 0]; g1b = cft[3 * (nn + 64) + 1];
            g1c = cft[3 * (nn + 64) + 2];
        }
        int cnts[4] = {wc[0], wc[1], wc[2], wc[3]};
#pragma unroll
        for (int seg = 0; seg < 4; ++seg) {
            const float4* sp = &sgl[seg * SEGCAP * 3];
            const int cnt = cnts[seg];
#pragma unroll 2
            for (int j = qw; j < cnt; j += 4) {
                float4 w0 = sp[3 * j + 0], w1 = sp[3 * j + 1], w2 = sp[3 * j + 2];
                float bb = fmaf(w0.y, z, w0.x);
                bb = fmaf(w1.x, zz, bb);
                bb = fmaf(w0.z, x, bb);
                bb = fmaf(w1.y, xx, bb);
                bb = fmaf(w1.w, zx, bb);
                float cy = fmaf(w2.x, z, w0.w);
                cy = fmaf(w2.y, x, cy);
#pragma unroll
                for (int i = 0; i < 4; ++i) {
                    float qv = fmaf(w1.z, yy[i], fmaf(cy, y[i], bb));
                    float rr = exp2_fast(qv);
                    aA[i] = fmaf(rr, w2.z, aA[i]);
                    aB[i] = fmaf(rr, w2.w, aB[i]);
                }
            }
        }
        __syncthreads();
    }
#pragma unroll
    for (int i = 0; i < 4; ++i) {
        cbuf[qw][s][i][0] = aA[i];
        cbuf[qw][s][i][1] = aB[i];
    }
    __syncthreads();
    const int s2 = t >> 2, i2 = t & 3;
    float A = cbuf[0][s2][i2][0] + cbuf[1][s2][i2][0]
            + cbuf[2][s2][i2][0] + cbuf[3][s2][i2][0];
    float B = cbuf[0][s2][i2][1] + cbuf[1][s2][i2][1]
            + cbuf[2][s2][i2][1] + cbuf[3][s2][i2][1];
    const int dz2 = s2 >> 4, dx2 = (s2 >> 1) & 7, dyq2 = s2 & 1;
    const int iz2 = bz * 4 + dz2, ix2 = bx * 8 + dx2;
    const int iy2 = by * 8 + dyq2 * 4 + i2;
    out[(iz2 * 64 + ix2) * 64 + iy2] = (u32)f2bf(B) | ((u32)f2bf(A) << 16);
}

// ---------------- last-resort fallback (no workspace, r9) ----------------
__global__ __launch_bounds__(256, 4) void vox_fallback(
    const float* __restrict__ pos, const float* __restrict__ cov,
    const float* __restrict__ dA,  const float* __restrict__ dB,
    u32* __restrict__ out, int N)
{
    __shared__ float4 sg[256 * 3];
    __shared__ float  cbuf[4][64][4][2];
    __shared__ int    wcnt[4];

    const int t = threadIdx.x, qw = t >> 6, lane = t & 63, s = lane;
    const int b = blockIdx.x;
    const int bz = b >> 6, bx = (b >> 3) & 7, by = b & 7;
    const int dz = s >> 4, dx = (s >> 1) & 7, dyq = s & 1;
    const int iz = bz * 4 + dz, ix = bx * 8 + dx, iy0 = by * 8 + dyq * 4;

    const float step = 2.0f / 63.0f;
    const float z = -1.0f + step * (float)iz;
    const float x = -1.0f + step * (float)ix;
    const float zz = z * z, xx = x * x, zx = z * x;
    float y[4], yy[4];
#pragma unroll
    for (int i = 0; i < 4; ++i) {
        y[i] = -1.0f + step * (float)(iy0 + i);
        yy[i] = y[i] * y[i];
    }
    const float zc = -1.0f + step * ((float)(bz * 4) + 1.5f);
    const float xc = -1.0f + step * ((float)(bx * 8) + 3.5f);
    const float yc = -1.0f + step * ((float)(by * 8) + 3.5f);
    const float hz = 1.5f * step, hx = 3.5f * step, hy = 3.5f * step;

    float aA[4] = {0.f, 0.f, 0.f, 0.f};
    float aB[4] = {0.f, 0.f, 0.f, 0.f};

    for (int cb = 0; cb < N; cb += 256) {
        int n = cb + t;
        bool pred = false;
        float4 F0, F1, F2;
        if (n < N) {
            const float sc = -0.7213475204444817f;
            float p0 = pos[3 * n + 0], p1 = pos[3 * n + 1], p2 = pos[3 * n + 2];
            const float* c = cov + 9 * n;
            float c00 = c[0], c01 = c[1], c02 = c[2];
            float c10 = c[3], c11 = c[4], c12 = c[5];
            float c20 = c[6], c21 = c[7], c22 = c[8];
            float s01 = c01 + c10, s02 = c02 + c20, s12 = c12 + c21;
            float k0 = sc * (c00 * p0 * p0 + c11 * p1 * p1 + c22 * p2 * p2
                             + s01 * p0 * p1 + s02 * p0 * p2 + s12 * p1 * p2);
            float kz = -sc * (2.0f * c00 * p0 + s01 * p1 + s02 * p2);
            float kx = -sc * (s01 * p0 + 2.0f * c11 * p1 + s12 * p2);
            float ky = -sc * (s02 * p0 + s12 * p1 + 2.0f * c22 * p2);
            F0 = make_float4(k0, kz, kx, ky);
            F1 = make_float4(sc * c00, sc * c11, sc * c22, sc * s01);
            F2 = make_float4(sc * s02, sc * s12, dA[n], dB[n]);
            pred = btest(F0, F1, F2, zc, xc, yc, hz, hx, hy);
        }
        u64 mask = __ballot(pred);
        int rank = __popcll(mask & ((1ull << lane) - 1ull));
        if (lane == 0) wcnt[qw] = __popcll(mask);
        __syncthreads();
        int off = 0;
#pragma unroll
        for (int w = 0; w < 4; ++w) if (w < qw) off += wcnt[w];
        const int total = wcnt[0] + wcnt[1] + wcnt[2] + wcnt[3];
        if (pred) {
            int p = off + rank;
            sg[3 * p + 0] = F0; sg[3 * p + 1] = F1; sg[3 * p + 2] = F2;
        }
        __syncthreads();
#pragma unroll 2
        for (int j = qw; j < total; j += 4) {
            float4 w0 = sg[3 * j + 0], w1 = sg[3 * j + 1], w2 = sg[3 * j + 2];
            float bb = fmaf(w0.y, z, w0.x);
            bb = fmaf(w1.x, zz, bb);
            bb = fmaf(w0.z, x, bb);
            bb = fmaf(w1.y, xx, bb);
            bb = fmaf(w1.w, zx, bb);
            float cy = fmaf(w2.x, z, w0.w);
            cy = fmaf(w2.y, x, cy);
#pragma unroll
            for (int i = 0; i < 4; ++i) {
                float qv = fmaf(w1.z, yy[i], fmaf(cy, y[i], bb));
                float rr = exp2_fast(qv);
                aA[i] = fmaf(rr, w2.z, aA[i]);
                aB[i] = fmaf(rr, w2.w, aB[i]);
            }
        }
        __syncthreads();
    }
#pragma unroll
    for (int i = 0; i < 4; ++i) {
        cbuf[qw][s][i][0] = aA[i];
        cbuf[qw][s][i][1] = aB[i];
    }
    __syncthreads();
    const int s2 = t >> 2, i2 = t & 3;
    float A = cbuf[0][s2][i2][0] + cbuf[1][s2][i2][0]
            + cbuf[2][s2][i2][0] + cbuf[3][s2][i2][0];
    float B = cbuf[0][s2][i2][1] + cbuf[1][s2][i2][1]
            + cbuf[2][s2][i2][1] + cbuf[3][s2][i2][1];
    const int dz2 = s2 >> 4, dx2 = (s2 >> 1) & 7, dyq2 = s2 & 1;
    const int iz2 = bz * 4 + dz2, ix2 = bx * 8 + dx2;
    const int iy2 = by * 8 + dyq2 * 4 + i2;
    out[(iz2 * 64 + ix2) * 64 + iy2] = (u32)f2bf(B) | ((u32)f2bf(A) << 16);
}

extern "C" void kernel_launch(void* const* d_in, const int* in_sizes, int n_in,
                              void* d_out, int out_size, void* d_ws, size_t ws_size,
                              hipStream_t stream)
{
    const float* pos = (const float*)d_in[0];
    const float* cov = (const float*)d_in[1];
    const float* dA  = (const float*)d_in[2];
    const float* dB  = (const float*)d_in[3];
    const int N = in_sizes[0] / 3;          // 4096

    const size_t CFT_BYTES = (size_t)4096 * 48;          // 196608
    const size_t PWS_BYTES = (size_t)2 * VTOT * 8;       // 4 MiB

    if (N == 4096 && ws_size >= CFT_BYTES + PWS_BYTES) {
        float4* cft = (float4*)d_ws;
        float2* pws = (float2*)((char*)d_ws + CFT_BYTES);
        vox_prep<<<16, 256, 0, stream>>>(pos, cov, dA, dB, cft, N);
        vox_accum<<<2048, 256, 0, stream>>>(cft, pws);
        vox_pack<<<VTOT / 512, 256, 0, stream>>>(pws, (u32*)d_out);
    } else if (N == 4096 && ws_size >= CFT_BYTES) {
        float4* cft = (float4*)d_ws;
        vox_prep<<<16, 256, 0, stream>>>(pos, cov, dA, dB, cft, N);
        vox_main<<<1024, 256, 0, stream>>>(cft, (u32*)d_out);
    } else {
        vox_fallback<<<1024, 256, 0, stream>>>(pos, cov, dA, dB, (u32*)d_out, N);
    }
}